// Round 2
// baseline (329.552 us; speedup 1.0000x reference)
//
#include <hip/hip_runtime.h>

// Point transformer B=1 N=512 D=256 H=8 HD=32 CD=3 HID=682.
// rel-tensor trick: hidden[i,j,e] = silu(P[i,e]+b[e]-P[j,e]); rel_value path
// contracted as G[h,e] = sum_j w*hidden_v then G @ rv2^T (+rv2_b exactly, since
// softmax weights sum to 1). rb2_b cancels in softmax.
// k3 computes both bias-GEMM (+fused qk via block-diag q B-operand) and the
// G-GEMM with mfma_f32_16x16x32_bf16; silu evaluated per-lane directly in
// A-fragment layout (m=lane&15, k=(lane>>4)*8+idx), cvt_pk_bf16 -> MFMA.

#define NN 512
#define DD 256
#define HH 8
#define HIDN 682
#define QKSCALE 0.17677669529663687f

// workspace offsets (floats)
#define OFF_XN     0        // [512][256] LN1(x)
#define OFF_Q      131072   // [512][256] q fp32
#define OFF_KBH    262144   // u32 [512][128]: bf16 pair (k[j][2c],k[j][2c+1])
#define OFF_VPF    327680   // [512][256] v fp32
#define OFF_PBTF   458752   // [512][256] coords@rb1 (row j, e-contig)
#define OFF_PVEF   589824   // [256][512] coords@rv1 (row e, j-contig)
#define OFF_RB2F   720896   // u32 [8 ks][64 lane][4]: rb2 B-fragments, h-padded 16
#define OFF_RV2TF  722944   // [256][256] rv2T[e][c]
#define OFF_X2     788480   // [512][256]
#define OFF_XN2    919552   // [512][256]
#define OFF_H1     1050624  // [512][682]

typedef float  f32x4  __attribute__((ext_vector_type(4)));
typedef short  bf16x8 __attribute__((ext_vector_type(8)));
typedef unsigned int u32;
typedef unsigned short ushortt;

static __device__ __forceinline__ float wredSum(float v){
#pragma unroll
  for (int o = 1; o < 64; o <<= 1) v += __shfl_xor(v, o, 64);
  return v;
}
static __device__ __forceinline__ float wredMax(float v){
#pragma unroll
  for (int o = 1; o < 64; o <<= 1) v = fmaxf(v, __shfl_xor(v, o, 64));
  return v;
}
static __device__ __forceinline__ float fsilu(float x){
  return x * __builtin_amdgcn_rcpf(1.0f + __expf(-x));
}
// RNE f32x2 -> packed bf16 (src0 -> low half)
static __device__ __forceinline__ u32 cvtpk(float lo, float hi){
  u32 d; asm("v_cvt_pk_bf16_f32 %0, %1, %2" : "=v"(d) : "v"(lo), "v"(hi));
  return d;
}
static __device__ __forceinline__ float bflo(u32 d){
  union{u32 u; float f;} c; c.u = d << 16; return c.f;
}
static __device__ __forceinline__ float us2f(ushortt u){
  union{u32 u; float f;} c; c.u = ((u32)u) << 16; return c.f;
}
static __device__ __forceinline__ bf16x8 mkfrag(u32 a, u32 b, u32 c, u32 d){
  union{u32 u[4]; bf16x8 s;} f; f.u[0]=a; f.u[1]=b; f.u[2]=c; f.u[3]=d; return f.s;
}

// ---------- K1: LN1 + table builders ----------
__global__ __launch_bounds__(256) void k1_prep(
    const float* __restrict__ x, const float* __restrict__ coords,
    const float* __restrict__ ln1_w, const float* __restrict__ ln1_b,
    const float* __restrict__ rb1_w, const float* __restrict__ rv1_w,
    const float* __restrict__ rv2_w, const float* __restrict__ rb2_w,
    float* __restrict__ ws)
{
  __shared__ float r4[4];
  const int b = blockIdx.x, t = threadIdx.x;
  if (b < NN) {
    const int lane = t & 63, wid = t >> 6;
    const float v = x[b*DD + t];
    float s = wredSum(v);
    if (lane == 0) r4[wid] = s;
    __syncthreads();
    const float mu = (r4[0]+r4[1]+r4[2]+r4[3]) * (1.0f/DD);
    const float d = v - mu;
    float s2 = wredSum(d*d);
    __syncthreads();
    if (lane == 0) r4[wid] = s2;
    __syncthreads();
    const float var = (r4[0]+r4[1]+r4[2]+r4[3]) * (1.0f/DD);
    ws[OFF_XN + b*DD + t] = d*rsqrtf(var + 1e-5f)*ln1_w[t] + ln1_b[t];
    if (b < DD) ws[OFF_RV2TF + b*DD + t] = rv2_w[t*DD + b];  // rv2T[e=b][c=t]
  } else {
    const int b0 = b - NN;  // 0..3
    // PBTF[j][e]: j-slice [b0*128,+128), lanes over e
    {
      const float w0 = rb1_w[t*3], w1 = rb1_w[t*3+1], w2 = rb1_w[t*3+2];
      for (int jj = 0; jj < 128; ++jj) {
        const int j = b0*128 + jj;
        const float c0 = coords[j*3], c1 = coords[j*3+1], c2 = coords[j*3+2];
        ws[OFF_PBTF + j*DD + t] = c0*w0 + c1*w1 + c2*w2;
      }
    }
    // PVEF[e][j]: j-slice [b0*128,+128) x all e; lanes over j (coalesced)
    {
      const int j = b0*128 + (t & 127), eh = t >> 7;
      const float c0 = coords[j*3], c1 = coords[j*3+1], c2 = coords[j*3+2];
      for (int ee = 0; ee < 128; ++ee) {
        const int e = eh*128 + ee;
        ws[OFF_PVEF + e*NN + j] = c0*rv1_w[e*3] + c1*rv1_w[e*3+1] + c2*rv1_w[e*3+2];
      }
    }
    // rb2 B-fragments: B[k=e,col=h(<8, pad16 zero)], elem r: e=ks*32+lg*8+r
    if (b0 == 0) {
      u32* RBF = (u32*)(ws + OFF_RB2F);
      const int l = t & 63, lm = l & 15, lg = (l >> 4) & 3, kq = t >> 6;
#pragma unroll
      for (int g = 0; g < 2; ++g) {
        const int ks = g*4 + kq;
        u32 dw[4];
#pragma unroll
        for (int dd = 0; dd < 4; ++dd) {
          const int e0 = ks*32 + lg*8 + 2*dd;
          const float f0 = (lm < HH) ? rb2_w[lm*DD + e0]     : 0.f;
          const float f1 = (lm < HH) ? rb2_w[lm*DD + e0 + 1] : 0.f;
          dw[dd] = cvtpk(f0, f1);
        }
        uint4 q4; q4.x = dw[0]; q4.y = dw[1]; q4.z = dw[2]; q4.w = dw[3];
        *(uint4*)(RBF + (ks*64 + l)*4) = q4;
      }
    }
  }
}

// ---------- K2: QKV GEMM (broadcast x rows via uniform s_load) ----------
__global__ __launch_bounds__(256) void k2_qkv(
    const float* __restrict__ xn, const float* __restrict__ qkv_w,
    const float* __restrict__ qkv_b, float* __restrict__ qout,
    float* __restrict__ kbh, float* __restrict__ vpf)
{
  const int i0 = blockIdx.x*4, rep = blockIdx.y, t = threadIdx.x;
  const int o = rep*DD + t;
  float acc[4];
  const float b = qkv_b[o];
#pragma unroll
  for (int r = 0; r < 4; ++r) acc[r] = b;
  const float* wrow = qkv_w + (size_t)o*DD;
  for (int dd = 0; dd < DD; dd += 4) {
    const float4 w4 = *(const float4*)(wrow + dd);
#pragma unroll
    for (int r = 0; r < 4; ++r) {
      const float4 xv = *(const float4*)(xn + (i0+r)*DD + dd);  // uniform -> s_load
      acc[r] += xv.x*w4.x + xv.y*w4.y + xv.z*w4.z + xv.w*w4.w;
    }
  }
  if (rep == 0) {
#pragma unroll
    for (int r = 0; r < 4; ++r) qout[(i0+r)*DD + t] = acc[r];
  } else if (rep == 1) {  // k -> bf16 channel-pair dwords [j][128]
    u32* KB = (u32*)kbh;
#pragma unroll
    for (int r = 0; r < 4; ++r) {
      const float part = __shfl_xor(acc[r], 1);
      if ((t & 1) == 0) KB[(i0+r)*128 + (t >> 1)] = cvtpk(acc[r], part);
    }
  } else {
#pragma unroll
    for (int r = 0; r < 4; ++r) vpf[(i0+r)*DD + t] = acc[r];
  }
}

// ---------- K3: fused scores(MFMA)+softmax+context(MFMA)+residual+LN2 ----------
__global__ __launch_bounds__(512, 6) void k3_attn(
    const float* __restrict__ x, const float* __restrict__ coords,
    const float* __restrict__ rb1_w, const float* __restrict__ rb1_b,
    const float* __restrict__ rv1_w, const float* __restrict__ rv1_b,
    const float* __restrict__ rv2_b, const float* __restrict__ ln2_w,
    const float* __restrict__ ln2_b,
    const float* __restrict__ qbuf, const float* __restrict__ pbtf,
    const float* __restrict__ pvef, const float* __restrict__ kbhf,
    const float* __restrict__ rb2f, const float* __restrict__ rv2tf,
    const float* __restrict__ vpf,
    float* __restrict__ x2out, float* __restrict__ xn2out)
{
  __shared__ __align__(16) float pbI[DD];
  __shared__ __align__(16) float pvI[DD];
  __shared__ __align__(16) float qI[DD];
  __shared__ __align__(16) float uni[4352];   // swl [8][513] f32  UNION  wtl [512][17] bf16
  __shared__ __align__(16) float GhL[HH*258];
  __shared__ __align__(16) float c1h[2*DD];
  __shared__ float red[8];
  float* swl = uni;
  ushortt* wtl = (ushortt*)uni;

  const int i = blockIdx.x, t = threadIdx.x;
  const int lane = t & 63, wid = t >> 6;
  const int lm = lane & 15, lg = lane >> 4;

  if (t < DD) {  // fp32 i-side projections (bias folded), q row
    const float c0 = coords[i*3], c1 = coords[i*3+1], c2 = coords[i*3+2];
    pbI[t] = c0*rb1_w[t*3] + c1*rb1_w[t*3+1] + c2*rb1_w[t*3+2] + rb1_b[t];
    pvI[t] = c0*rv1_w[t*3] + c1*rv1_w[t*3+1] + c2*rv1_w[t*3+2] + rv1_b[t];
    qI[t]  = qbuf[i*DD + t];
  }
  __syncthreads();

  // ---- Phase A: swl[h][j] = sum_e silu(pbI-P[j,e])*W[e,h] + qk  (MFMA) ----
  {
    const int jbase = wid*64;
    f32x4 z = {0.f,0.f,0.f,0.f};
    f32x4 acc[4] = {z,z,z,z};
    const u32* RBF = (const u32*)rb2f;
    for (int ks = 0; ks < 8; ++ks) {          // silu-GEMM: K=256
      const uint4 bd = *(const uint4*)(RBF + (ks*64 + lane)*4);
      const bf16x8 bfr = mkfrag(bd.x, bd.y, bd.z, bd.w);
      const float4 pb0 = *(const float4*)(pbI + ks*32 + lg*8);
      const float4 pb1 = *(const float4*)(pbI + ks*32 + lg*8 + 4);
#pragma unroll
      for (int jt = 0; jt < 4; ++jt) {
        const int j = jbase + jt*16 + lm;     // A row m = lane&15
        const float* pr = pbtf + j*DD + ks*32 + lg*8;
        const float4 p0 = *(const float4*)pr;
        const float4 p1 = *(const float4*)(pr + 4);
        const bf16x8 afr = mkfrag(
          cvtpk(fsilu(pb0.x-p0.x), fsilu(pb0.y-p0.y)),
          cvtpk(fsilu(pb0.z-p0.z), fsilu(pb0.w-p0.w)),
          cvtpk(fsilu(pb1.x-p1.x), fsilu(pb1.y-p1.y)),
          cvtpk(fsilu(pb1.z-p1.z), fsilu(pb1.w-p1.w)));
        acc[jt] = __builtin_amdgcn_mfma_f32_16x16x32_bf16(afr, bfr, acc[jt], 0, 0, 0);
      }
    }
    const u32* KB = (const u32*)kbhf;
    for (int hq = 0; hq < 8; ++hq) {          // qk fused: B = block-diag q*scale
      const float4 q0 = *(const float4*)(qI + hq*32 + lg*8);
      const float4 q1 = *(const float4*)(qI + hq*32 + lg*8 + 4);
      const float m = (lm == hq) ? QKSCALE : 0.f;
      const bf16x8 bfr = mkfrag(cvtpk(q0.x*m, q0.y*m), cvtpk(q0.z*m, q0.w*m),
                                cvtpk(q1.x*m, q1.y*m), cvtpk(q1.z*m, q1.w*m));
#pragma unroll
      for (int jt = 0; jt < 4; ++jt) {
        const int j = jbase + jt*16 + lm;
        const uint4 ad = *(const uint4*)(KB + j*128 + hq*16 + lg*4);
        const bf16x8 afr = mkfrag(ad.x, ad.y, ad.z, ad.w);
        acc[jt] = __builtin_amdgcn_mfma_f32_16x16x32_bf16(afr, bfr, acc[jt], 0, 0, 0);
      }
    }
    if (lm < HH) {  // D: col=lane&15(=h), row=(lane>>4)*4+g
#pragma unroll
      for (int jt = 0; jt < 4; ++jt)
#pragma unroll
        for (int g = 0; g < 4; ++g)
          swl[lm*513 + jbase + jt*16 + lg*4 + g] = acc[jt][g];
    }
  }
  __syncthreads();

  // ---- softmax: wave wid owns head wid (into regs) ----
  float sv[8];
  {
    float mm = -3.4e38f;
#pragma unroll
    for (int r = 0; r < 8; ++r) { sv[r] = swl[wid*513 + lane + r*64]; mm = fmaxf(mm, sv[r]); }
    mm = wredMax(mm);
    float sum = 0.f;
#pragma unroll
    for (int r = 0; r < 8; ++r) { sv[r] = __expf(sv[r] - mm); sum += sv[r]; }
    sum = wredSum(sum);
    const float rz = __builtin_amdgcn_rcpf(sum);
#pragma unroll
    for (int r = 0; r < 8; ++r) sv[r] *= rz;
  }
  __syncthreads();  // all swl reads done -> safe to overwrite union as wtl
#pragma unroll
  for (int r = 0; r < 8; ++r)
    wtl[(lane + r*64)*17 + wid] = (ushortt)(cvtpk(sv[r], 0.f) & 0xFFFFu);
  __syncthreads();

  // ---- Phase B: G^T[e,h] = sum_j silu(pvI[e]-Pv[j,e]) * w[j,h]  (MFMA) ----
  {
    f32x4 accB0 = {0.f,0.f,0.f,0.f}, accB1 = {0.f,0.f,0.f,0.f};
    const int mt0 = wid*2, mt1 = wid*2 + 1;
    const int e0 = mt0*16 + lm, e1 = mt1*16 + lm;   // A row m = lane&15
    const float pv0 = pvI[e0], pv1 = pvI[e1];
    for (int ks = 0; ks < 16; ++ks) {               // K = j = 512
      const int jr = ks*32 + lg*8;
      ushortt wv[8];
#pragma unroll
      for (int r = 0; r < 8; ++r) wv[r] = wtl[(jr + r)*17 + lm];
      const bf16x8 wfr = mkfrag((u32)wv[0] | ((u32)wv[1] << 16),
                                (u32)wv[2] | ((u32)wv[3] << 16),
                                (u32)wv[4] | ((u32)wv[5] << 16),
                                (u32)wv[6] | ((u32)wv[7] << 16));
      {
        const float* pr = pvef + e0*NN + jr;
        const float4 p0 = *(const float4*)pr, p1 = *(const float4*)(pr + 4);
        const bf16x8 afr = mkfrag(
          cvtpk(fsilu(pv0-p0.x), fsilu(pv0-p0.y)),
          cvtpk(fsilu(pv0-p0.z), fsilu(pv0-p0.w)),
          cvtpk(fsilu(pv0-p1.x), fsilu(pv0-p1.y)),
          cvtpk(fsilu(pv0-p1.z), fsilu(pv0-p1.w)));
        accB0 = __builtin_amdgcn_mfma_f32_16x16x32_bf16(afr, wfr, accB0, 0, 0, 0);
      }
      {
        const float* pr = pvef + e1*NN + jr;
        const float4 p0 = *(const float4*)pr, p1 = *(const float4*)(pr + 4);
        const bf16x8 afr = mkfrag(
          cvtpk(fsilu(pv1-p0.x), fsilu(pv1-p0.y)),
          cvtpk(fsilu(pv1-p0.z), fsilu(pv1-p0.w)),
          cvtpk(fsilu(pv1-p1.x), fsilu(pv1-p1.y)),
          cvtpk(fsilu(pv1-p1.z), fsilu(pv1-p1.w)));
        accB1 = __builtin_amdgcn_mfma_f32_16x16x32_bf16(afr, wfr, accB1, 0, 0, 0);
      }
    }
    if (lm < HH) {
#pragma unroll
      for (int g = 0; g < 4; ++g) {
        GhL[lm*258 + mt0*16 + lg*4 + g] = accB0[g];
        GhL[lm*258 + mt1*16 + lg*4 + g] = accB1[g];
      }
    }
  }

  // ---- Phase C: context1[c] = sum_j w[h(c),j] * v[j,c] ----
  {
    const int c = t & 255, half = t >> 8, h = c >> 5;
    float a0 = 0.f;
    for (int j = half*256; j < half*256 + 256; ++j)
      a0 += us2f(wtl[j*17 + h]) * vpf[j*DD + c];
    c1h[half*DD + c] = a0;
  }
  __syncthreads();

  // ---- Phase D: context2 = G @ rv2^T + rv2_b; residual + LN2 ----
  float x2v = 0.f;
  if (t < DD) {
    const int c = t, h = c >> 5;
    float a0 = 0.f;
    for (int e = 0; e < DD; ++e) a0 += GhL[h*258 + e] * rv2tf[e*DD + c];
    x2v = x[i*DD + c] + c1h[c] + c1h[DD + c] + a0 + rv2_b[c];
  }
  float s = wredSum(x2v);
  if (lane == 0) red[wid] = s;
  __syncthreads();
  const float mu = (red[0]+red[1]+red[2]+red[3]) * (1.0f/DD);
  const float dv = (t < DD) ? (x2v - mu) : 0.f;
  float s2 = wredSum(dv*dv);
  __syncthreads();
  if (lane == 0) red[wid] = s2;
  __syncthreads();
  const float var = (red[0]+red[1]+red[2]+red[3]) * (1.0f/DD);
  const float rstd = rsqrtf(var + 1e-5f);
  if (t < DD) {
    x2out[i*DD + t]  = x2v;
    xn2out[i*DD + t] = (x2v - mu)*rstd*ln2_w[t] + ln2_b[t];
  }
}

// ---------- K4: SwiGLU up-projections ----------
__global__ __launch_bounds__(256) void k4_ffn1(
    const float* __restrict__ xn2, const float* __restrict__ w1,
    const float* __restrict__ b1, const float* __restrict__ w2,
    const float* __restrict__ b2, float* __restrict__ h1)
{
  const int i0 = blockIdx.x*4, rep = blockIdx.y, t = threadIdx.x;
  const int o = rep*DD + t;
  if (o >= HIDN) return;
  float a1[4], a2[4];
  const float bb1 = b1[o], bb2 = b2[o];
#pragma unroll
  for (int r = 0; r < 4; ++r) { a1[r] = bb1; a2[r] = bb2; }
  const float* w1r = w1 + (size_t)o*DD;
  const float* w2r = w2 + (size_t)o*DD;
  for (int dd = 0; dd < DD; dd += 4) {
    const float4 u = *(const float4*)(w1r + dd);
    const float4 w = *(const float4*)(w2r + dd);
#pragma unroll
    for (int r = 0; r < 4; ++r) {
      const float4 xv = *(const float4*)(xn2 + (i0+r)*DD + dd);  // uniform -> s_load
      a1[r] += xv.x*u.x + xv.y*u.y + xv.z*u.z + xv.w*u.w;
      a2[r] += xv.x*w.x + xv.y*w.y + xv.z*w.z + xv.w*w.w;
    }
  }
#pragma unroll
  for (int r = 0; r < 4; ++r)
    h1[(size_t)(i0+r)*HIDN + o] = fsilu(a1[r]) * a2[r];
}

// ---------- K5: down-projection + residual ----------
__global__ __launch_bounds__(256) void k5_ffn2(
    const float* __restrict__ h1, const float* __restrict__ x2,
    const float* __restrict__ w3, const float* __restrict__ b3,
    float* __restrict__ out)
{
  const int i0 = blockIdx.x*2, t = threadIdx.x;
  float acc[2];
  acc[0] = b3[t] + x2[i0*DD + t];
  acc[1] = b3[t] + x2[(i0+1)*DD + t];
  const float* w3r = w3 + (size_t)t*HIDN;
  const float* h0 = h1 + (size_t)i0*HIDN;
  const float* h1r = h1 + (size_t)(i0+1)*HIDN;
  for (int e = 0; e < HIDN; e += 2) {
    const float2 w = *(const float2*)(w3r + e);
    acc[0] += h0[e]*w.x + h0[e+1]*w.y;    // h rows uniform -> s_load
    acc[1] += h1r[e]*w.x + h1r[e+1]*w.y;
  }
  out[i0*DD + t] = acc[0];
  out[(i0+1)*DD + t] = acc[1];
}

extern "C" void kernel_launch(void* const* d_in, const int* in_sizes, int n_in,
                              void* d_out, int out_size, void* d_ws, size_t ws_size,
                              hipStream_t stream) {
  (void)in_sizes; (void)n_in; (void)out_size; (void)ws_size;
  const float* x      = (const float*)d_in[0];
  const float* coords = (const float*)d_in[1];
  const float* ln1_w  = (const float*)d_in[2];
  const float* ln1_b  = (const float*)d_in[3];
  const float* ln2_w  = (const float*)d_in[4];
  const float* ln2_b  = (const float*)d_in[5];
  const float* qkv_w  = (const float*)d_in[6];
  const float* qkv_b  = (const float*)d_in[7];
  const float* rb1_w  = (const float*)d_in[8];
  const float* rb1_b  = (const float*)d_in[9];
  const float* rb2_w  = (const float*)d_in[10];
  /* d_in[11] = rb2_b cancels in softmax */
  const float* rv1_w  = (const float*)d_in[12];
  const float* rv1_b  = (const float*)d_in[13];
  const float* rv2_w  = (const float*)d_in[14];
  const float* rv2_b  = (const float*)d_in[15];
  const float* ffn_w1 = (const float*)d_in[16];
  const float* ffn_b1 = (const float*)d_in[17];
  const float* ffn_w2 = (const float*)d_in[18];
  const float* ffn_b2 = (const float*)d_in[19];
  const float* ffn_w3 = (const float*)d_in[20];
  const float* ffn_b3 = (const float*)d_in[21];
  float* ws  = (float*)d_ws;
  float* out = (float*)d_out;

  k1_prep<<<NN + 4, DD, 0, stream>>>(x, coords, ln1_w, ln1_b, rb1_w, rv1_w, rv2_w, rb2_w, ws);
  k2_qkv<<<dim3(NN/4, 3), DD, 0, stream>>>(ws + OFF_XN, qkv_w, qkv_b,
                                           ws + OFF_Q, ws + OFF_KBH, ws + OFF_VPF);
  k3_attn<<<NN, 512, 0, stream>>>(x, coords, rb1_w, rb1_b, rv1_w, rv1_b, rv2_b,
                                  ln2_w, ln2_b,
                                  ws + OFF_Q, ws + OFF_PBTF, ws + OFF_PVEF,
                                  ws + OFF_KBH, ws + OFF_RB2F, ws + OFF_RV2TF,
                                  ws + OFF_VPF, ws + OFF_X2, ws + OFF_XN2);
  k4_ffn1<<<dim3(NN/4, 3), DD, 0, stream>>>(ws + OFF_XN2, ffn_w1, ffn_b1, ffn_w2, ffn_b2,
                                            ws + OFF_H1);
  k5_ffn2<<<NN/2, DD, 0, stream>>>(ws + OFF_H1, ws + OFF_X2, ffn_w3, ffn_b3, out);
}

// Round 4
// 259.605 us; speedup vs baseline: 1.2694x; 1.2694x over previous
//
#include <hip/hip_runtime.h>

// Point transformer B=1 N=512 D=256 H=8 HD=32 CD=3 HID=682.
// hidden[i,j,e] = silu(aI[e] - p[j,e]) with aI = coords[i]@W1 + b (i-side),
// p[j,e] = coords[j]@W1 (j-side).  exp-factorization: e^{-(aI-p)} = e^{-aI}*e^{p},
// so tables store (p, e^p) and the inner loop needs only rcp (1 trans/elem).
// rel_value path contracted as G[h,e]=sum_j w*hidden_v, then G @ rv2^T + rv2_b
// (exact: softmax rows sum to 1). rb2_b cancels in softmax.
// All MFMA A-operands come from tables pre-swizzled into fragment order so
// every hot load is 64-lane contiguous.
// ws footprint capped at 1,596,416 floats (proven-safe size): W3P is packed
// by k4 into the region Q/VPF vacate after k3.

#define NN 512
#define DD 256
#define HH 8
#define HIDN 682
#define QKSCALE 0.17677669529663687f

// ---- workspace layout (floats); end = 1,596,416 fl = 6.39 MB ----
#define OFF_XN     0        // [512][256] LN1(x)          (k1 -> k2)
#define OFF_X2     0        //  reuse after k2: x+attn    (k3 -> k5)
#define OFF_Q      131072   // [512][256] q fp32          (k2 -> k3)
#define OFF_W3P    131072   //  reuse after k3: f2[341][256] w3 k-major (k4 -> k5)
#define OFF_VPF    262144   // [512][256] v fp32          (k2 -> k3)
#define OFF_RV2T   393216   // [256][256] rv2T[e][c]      (k1 -> k3)
#define OFF_RB2F   458752   // u32[8][64][4] rb2 B-frags  (k1 -> k3)
#define OFF_KF     460800   // u32[32][8][4][16][4] k A-frags (k2 -> k3)
#define OFF_PBF    526336   // f4[32][8][4][4][16] (p,e^p,p,e^p) (k1 -> k3)
#define OFF_H1     526336   //  reuse after k3: [512][682] swiglu (k4 -> k5)
#define OFF_PVF    788480   // f4[16][16][4][4][16]       (k1 -> k3)
#define OFF_QKVP   1050624  // f4[64][768] qkv_w k-major  (k1 -> k2)
#define OFF_XN2    1050624  //  reuse after k2: LN2 out   (k3 -> k4)
#define OFF_W12P   1247232  // f4[64][682][2] (w1,w2) k-major (k1 -> k4)

typedef float  f32x4  __attribute__((ext_vector_type(4)));
typedef short  bf16x8 __attribute__((ext_vector_type(8)));
typedef unsigned int u32;
typedef unsigned short ushortt;

static __device__ __forceinline__ float wredSum(float v){
#pragma unroll
  for (int o = 1; o < 64; o <<= 1) v += __shfl_xor(v, o, 64);
  return v;
}
static __device__ __forceinline__ float wredMax(float v){
#pragma unroll
  for (int o = 1; o < 64; o <<= 1) v = fmaxf(v, __shfl_xor(v, o, 64));
  return v;
}
static __device__ __forceinline__ float fsilu(float x){
  return x * __builtin_amdgcn_rcpf(1.0f + __expf(-x));
}
static __device__ __forceinline__ u32 cvtpk(float lo, float hi){
  u32 d; asm("v_cvt_pk_bf16_f32 %0, %1, %2" : "=v"(d) : "v"(lo), "v"(hi));
  return d;
}
static __device__ __forceinline__ float us2f(ushortt u){
  union{u32 u; float f;} c; c.u = ((u32)u) << 16; return c.f;
}
static __device__ __forceinline__ bf16x8 mkfrag(u32 a, u32 b, u32 c, u32 d){
  union{u32 u[4]; bf16x8 s;} f; f.u[0]=a; f.u[1]=b; f.u[2]=c; f.u[3]=d; return f.s;
}
static __device__ __forceinline__ float dot4(float4 a, float4 b){
  return a.x*b.x + a.y*b.y + a.z*b.z + a.w*b.w;
}

// ---------- K1: LN1 + table/packing builders (1033 blocks) ----------
__global__ __launch_bounds__(256) void k1_prep(
    const float* __restrict__ x, const float* __restrict__ coords,
    const float* __restrict__ ln1_w, const float* __restrict__ ln1_b,
    const float* __restrict__ rb1_w, const float* __restrict__ rv1_w,
    const float* __restrict__ rv2_w, const float* __restrict__ rb2_w,
    const float* __restrict__ qkv_w, const float* __restrict__ w1,
    const float* __restrict__ w2, float* __restrict__ ws)
{
  __shared__ float r4[4];
  const int b = blockIdx.x, t = threadIdx.x;
  if (b < 512) {                       // ---- LN1 ----
    const int lane = t & 63, wid = t >> 6;
    const float v = x[b*DD + t];
    float s = wredSum(v);
    if (lane == 0) r4[wid] = s;
    __syncthreads();
    const float mu = (r4[0]+r4[1]+r4[2]+r4[3]) * (1.0f/DD);
    const float d = v - mu;
    float s2 = wredSum(d*d);
    __syncthreads();
    if (lane == 0) r4[wid] = s2;
    __syncthreads();
    const float var = (r4[0]+r4[1]+r4[2]+r4[3]) * (1.0f/DD);
    ws[OFF_XN + b*DD + t] = d*rsqrtf(var + 1e-5f)*ln1_w[t] + ln1_b[t];
  } else if (b < 768) {                // ---- rv2T[e][c] = rv2_w[c][e] ----
    const int e = b - 512;
    ws[OFF_RV2T + e*DD + t] = rv2_w[t*DD + e];
  } else if (b == 768) {               // ---- rb2 B-fragments ----
    u32* RBF = (u32*)(ws + OFF_RB2F);
    const int l = t & 63, lm = l & 15, lg = (l >> 4) & 3, kq = t >> 6;
#pragma unroll
    for (int g = 0; g < 2; ++g) {
      const int ks = g*4 + kq;
      u32 dw[4];
#pragma unroll
      for (int dd = 0; dd < 4; ++dd) {
        const int e0 = ks*32 + lg*8 + 2*dd;
        const float f0 = (lm < HH) ? rb2_w[lm*DD + e0]     : 0.f;
        const float f1 = (lm < HH) ? rb2_w[lm*DD + e0 + 1] : 0.f;
        dw[dd] = cvtpk(f0, f1);
      }
      uint4 q4; q4.x = dw[0]; q4.y = dw[1]; q4.z = dw[2]; q4.w = dw[3];
      *(uint4*)(RBF + (ks*64 + l)*4) = q4;
    }
  } else if (b < 833) {                // ---- PBF: [jt][ks][lg][q][lm] f4 ----
    float4* dst = (float4*)(ws + OFF_PBF);
#pragma unroll
    for (int k = 0; k < 4; ++k) {
      const int L4 = (b - 769)*1024 + k*256 + t;
      const int lm = L4 & 15, q = (L4>>4)&3, lg = (L4>>6)&3, ks = (L4>>8)&7, jt = L4>>11;
      const int j = jt*16 + lm, e0 = ks*32 + lg*8 + q*2;
      const float c0 = coords[j*3], c1 = coords[j*3+1], c2 = coords[j*3+2];
      const float p0 = c0*rb1_w[e0*3]   + c1*rb1_w[e0*3+1] + c2*rb1_w[e0*3+2];
      const float p1 = c0*rb1_w[e0*3+3] + c1*rb1_w[e0*3+4] + c2*rb1_w[e0*3+5];
      dst[L4] = make_float4(p0, __expf(p0), p1, __expf(p1));
    }
  } else if (b < 897) {                // ---- PVF: [et][ks][lg][q][lm] f4 ----
    float4* dst = (float4*)(ws + OFF_PVF);
#pragma unroll
    for (int k = 0; k < 4; ++k) {
      const int L4 = (b - 833)*1024 + k*256 + t;
      const int lm = L4 & 15, q = (L4>>4)&3, lg = (L4>>6)&3, ks = (L4>>8)&15, et = L4>>12;
      const int e = et*16 + lm, j0 = ks*32 + lg*8 + q*2;
      const float w0 = rv1_w[e*3], w1_ = rv1_w[e*3+1], w2_ = rv1_w[e*3+2];
      const float p0 = coords[j0*3]*w0 + coords[j0*3+1]*w1_ + coords[j0*3+2]*w2_;
      const float p1 = coords[j0*3+3]*w0 + coords[j0*3+4]*w1_ + coords[j0*3+5]*w2_;
      dst[L4] = make_float4(p0, __expf(p0), p1, __expf(p1));
    }
  } else if (b < 945) {                // ---- QKVP: f4[k4][768] ----
    float4* dst = (float4*)(ws + OFF_QKVP);
#pragma unroll
    for (int k = 0; k < 4; ++k) {
      const int L4 = (b - 897)*1024 + k*256 + t;
      const int O = L4 % 768, k4 = L4 / 768;
      dst[L4] = *(const float4*)(qkv_w + O*DD + k4*4);
    }
  } else {                             // ---- W12P: f4[k4][682][2] ----
    float4* dst = (float4*)(ws + OFF_W12P);
    for (int L4 = (b - 945)*256 + t; L4 < 87296; L4 += 88*256) {
      const int pr = L4 & 1, rest = L4 >> 1;
      const int O = rest % 682, k4 = rest / 682;
      dst[L4] = *(const float4*)((pr ? w2 : w1) + O*DD + k4*4);
    }
  }
}

// ---------- K2: QKV GEMM, coalesced k-major weights, s_load x rows ----------
__global__ __launch_bounds__(256) void k2_qkv(
    float* __restrict__ ws, const float* __restrict__ qkv_b)
{
  const int i0 = blockIdx.x*2, rep = blockIdx.y, t = threadIdx.x;
  const int O = rep*DD + t;
  const float4* xn4 = (const float4*)(ws + OFF_XN);
  const float4* wp4 = (const float4*)(ws + OFF_QKVP);
  float a0 = qkv_b[O], a1 = a0;
  for (int k4 = 0; k4 < 64; ++k4) {
    const float4 w = wp4[k4*768 + O];
    const float4 x0 = xn4[i0*64 + k4];        // uniform -> s_load
    const float4 x1 = xn4[i0*64 + 64 + k4];
    a0 += dot4(x0, w);
    a1 += dot4(x1, w);
  }
  if (rep == 0) {
    ws[OFF_Q + i0*DD + t] = a0;
    ws[OFF_Q + (i0+1)*DD + t] = a1;
  } else if (rep == 1) {                      // k -> bf16 A-fragment layout
    u32* KF = (u32*)(ws + OFF_KF);
    const int c = t;
    const float p0 = __shfl_xor(a0, 1);
    const float p1 = __shfl_xor(a1, 1);
    if ((c & 1) == 0) {
      const int hq = c >> 5, lgk = (c >> 3) & 3, dw = (c & 7) >> 1;
      const int jt0_ = i0 >> 4, lm0 = i0 & 15;
      KF[(((jt0_*8 + hq)*4 + lgk)*16 + lm0)*4 + dw] = cvtpk(a0, p0);
      const int j1 = i0 + 1, jt1_ = j1 >> 4, lm1 = j1 & 15;
      KF[(((jt1_*8 + hq)*4 + lgk)*16 + lm1)*4 + dw] = cvtpk(a1, p1);
    }
  } else {
    ws[OFF_VPF + i0*DD + t] = a0;
    ws[OFF_VPF + (i0+1)*DD + t] = a1;
  }
}

// ---------- K3: fused scores(MFMA)+softmax+context(MFMA)+residual+LN2 ----------
__global__ __launch_bounds__(512, 4) void k3_attn(
    const float* __restrict__ x, const float* __restrict__ coords,
    const float* __restrict__ rb1_w, const float* __restrict__ rb1_b,
    const float* __restrict__ rv1_w, const float* __restrict__ rv1_b,
    const float* __restrict__ rv2_b, const float* __restrict__ ln2_w,
    const float* __restrict__ ln2_b, float* __restrict__ ws)
{
  __shared__ __align__(16) float aI[DD], eIl[DD], pvIl[DD], evIl[DD], qI[DD];
  __shared__ __align__(16) float uni[4352];   // swl[8][513] f32 U wtl[512][17] bf16
  __shared__ __align__(16) float GhL[HH*258];
  __shared__ __align__(16) float c1h[2*DD];
  __shared__ float red[8];
  float* swl = uni;
  ushortt* wtl = (ushortt*)uni;

  const int i = blockIdx.x, t = threadIdx.x;
  const int lane = t & 63, wid = t >> 6, lm = lane & 15, lg = lane >> 4;
  const float* qbuf = ws + OFF_Q;
  const float4* PBF4 = (const float4*)(ws + OFF_PBF);
  const float4* PVF4 = (const float4*)(ws + OFF_PVF);
  const uint4*  KF4  = (const uint4*)(ws + OFF_KF);
  const u32*    RBF  = (const u32*)(ws + OFF_RB2F);
  const float*  rv2t = ws + OFF_RV2T;
  const float*  vpf  = ws + OFF_VPF;

  if (t < DD) {
    const float c0 = coords[i*3], c1 = coords[i*3+1], c2 = coords[i*3+2];
    const float a  = c0*rb1_w[t*3] + c1*rb1_w[t*3+1] + c2*rb1_w[t*3+2] + rb1_b[t];
    aI[t] = a;  eIl[t] = __expf(-a);
    const float pv = c0*rv1_w[t*3] + c1*rv1_w[t*3+1] + c2*rv1_w[t*3+2] + rv1_b[t];
    pvIl[t] = pv; evIl[t] = __expf(-pv);
    qI[t] = qbuf[i*DD + t];
  }
  __syncthreads();

  // ---- Phase A: scores via silu-GEMM (K=256) + fused qk (block-diag B) ----
  {
    f32x4 z4 = {0.f,0.f,0.f,0.f};
    f32x4 acc[4] = {z4,z4,z4,z4};
    const int jt0 = wid*4;
    for (int ks = 0; ks < 8; ++ks) {
      const uint4 bd = *(const uint4*)(RBF + (ks*64 + lane)*4);
      const bf16x8 bfr = mkfrag(bd.x, bd.y, bd.z, bd.w);
      const float4 aA0 = *(const float4*)&aI[ks*32 + lg*8];
      const float4 aA1 = *(const float4*)&aI[ks*32 + lg*8 + 4];
      const float4 eA0 = *(const float4*)&eIl[ks*32 + lg*8];
      const float4 eA1 = *(const float4*)&eIl[ks*32 + lg*8 + 4];
#pragma unroll
      for (int jt = 0; jt < 4; ++jt) {
        const float4* src = PBF4 + ((jt0+jt)*32 + ks*4 + lg)*64 + lm;
        const float4 g0 = src[0], g1 = src[16], g2 = src[32], g3 = src[48];
        const float s0 = (aA0.x-g0.x)*__builtin_amdgcn_rcpf(fmaf(eA0.x,g0.y,1.f));
        const float s1 = (aA0.y-g0.z)*__builtin_amdgcn_rcpf(fmaf(eA0.y,g0.w,1.f));
        const float s2 = (aA0.z-g1.x)*__builtin_amdgcn_rcpf(fmaf(eA0.z,g1.y,1.f));
        const float s3 = (aA0.w-g1.z)*__builtin_amdgcn_rcpf(fmaf(eA0.w,g1.w,1.f));
        const float s4 = (aA1.x-g2.x)*__builtin_amdgcn_rcpf(fmaf(eA1.x,g2.y,1.f));
        const float s5 = (aA1.y-g2.z)*__builtin_amdgcn_rcpf(fmaf(eA1.y,g2.w,1.f));
        const float s6 = (aA1.z-g3.x)*__builtin_amdgcn_rcpf(fmaf(eA1.z,g3.y,1.f));
        const float s7 = (aA1.w-g3.z)*__builtin_amdgcn_rcpf(fmaf(eA1.w,g3.w,1.f));
        const bf16x8 afr = mkfrag(cvtpk(s0,s1), cvtpk(s2,s3), cvtpk(s4,s5), cvtpk(s6,s7));
        acc[jt] = __builtin_amdgcn_mfma_f32_16x16x32_bf16(afr, bfr, acc[jt], 0, 0, 0);
      }
    }
#pragma unroll
    for (int hq = 0; hq < 8; ++hq) {
      const float4 q0 = *(const float4*)&qI[hq*32 + lg*8];
      const float4 q1 = *(const float4*)&qI[hq*32 + lg*8 + 4];
      const float m = (lm == hq) ? QKSCALE : 0.f;
      const bf16x8 bfr = mkfrag(cvtpk(q0.x*m, q0.y*m), cvtpk(q0.z*m, q0.w*m),
                                cvtpk(q1.x*m, q1.y*m), cvtpk(q1.z*m, q1.w*m));
#pragma unroll
      for (int jt = 0; jt < 4; ++jt) {
        const uint4 ad = KF4[(((jt0+jt)*8 + hq)*4 + lg)*16 + lm];
        const bf16x8 afr = mkfrag(ad.x, ad.y, ad.z, ad.w);
        acc[jt] = __builtin_amdgcn_mfma_f32_16x16x32_bf16(afr, bfr, acc[jt], 0, 0, 0);
      }
    }
    if (lm < HH) {  // D: col=lane&15(=h), row=(lane>>4)*4+g
#pragma unroll
      for (int jt = 0; jt < 4; ++jt)
#pragma unroll
        for (int g = 0; g < 4; ++g)
          swl[lm*513 + wid*64 + jt*16 + lg*4 + g] = acc[jt][g];
    }
  }
  __syncthreads();

  // ---- softmax: wave wid owns head wid ----
  float sv[8];
  {
    float mm = -3.4e38f;
#pragma unroll
    for (int r = 0; r < 8; ++r) { sv[r] = swl[wid*513 + lane + r*64]; mm = fmaxf(mm, sv[r]); }
    mm = wredMax(mm);
    float sum = 0.f;
#pragma unroll
    for (int r = 0; r < 8; ++r) { sv[r] = __expf(sv[r] - mm); sum += sv[r]; }
    sum = wredSum(sum);
    const float rz = __builtin_amdgcn_rcpf(sum);
#pragma unroll
    for (int r = 0; r < 8; ++r) sv[r] *= rz;
  }
  __syncthreads();
#pragma unroll
  for (int r = 0; r < 8; ++r)
    wtl[(lane + r*64)*17 + wid] = (ushortt)(cvtpk(sv[r], 0.f) & 0xFFFFu);
  __syncthreads();

  // ---- Phase B: G^T[e,h] = sum_j silu(pvI[e]-Pv[j,e]) * w[j,h] (MFMA, K=512) ----
  {
    f32x4 z4 = {0.f,0.f,0.f,0.f};
    f32x4 accB0 = z4, accB1 = z4;
    const int et0 = wid*2;
    const int eR0 = et0*16 + lm, eR1 = eR0 + 16;
    const float aV0 = pvIl[eR0], eV0 = evIl[eR0];
    const float aV1 = pvIl[eR1], eV1 = evIl[eR1];
    for (int ks = 0; ks < 16; ++ks) {
      ushortt wv[8];
#pragma unroll
      for (int r = 0; r < 8; ++r) wv[r] = wtl[(ks*32 + lg*8 + r)*17 + lm];
      const bf16x8 wfr = mkfrag((u32)wv[0] | ((u32)wv[1] << 16),
                                (u32)wv[2] | ((u32)wv[3] << 16),
                                (u32)wv[4] | ((u32)wv[5] << 16),
                                (u32)wv[6] | ((u32)wv[7] << 16));
      {
        const float4* src = PVF4 + ((et0*16 + ks)*4 + lg)*64 + lm;
        const float4 g0 = src[0], g1 = src[16], g2 = src[32], g3 = src[48];
        const float s0 = (aV0-g0.x)*__builtin_amdgcn_rcpf(fmaf(eV0,g0.y,1.f));
        const float s1 = (aV0-g0.z)*__builtin_amdgcn_rcpf(fmaf(eV0,g0.w,1.f));
        const float s2 = (aV0-g1.x)*__builtin_amdgcn_rcpf(fmaf(eV0,g1.y,1.f));
        const float s3 = (aV0-g1.z)*__builtin_amdgcn_rcpf(fmaf(eV0,g1.w,1.f));
        const float s4 = (aV0-g2.x)*__builtin_amdgcn_rcpf(fmaf(eV0,g2.y,1.f));
        const float s5 = (aV0-g2.z)*__builtin_amdgcn_rcpf(fmaf(eV0,g2.w,1.f));
        const float s6 = (aV0-g3.x)*__builtin_amdgcn_rcpf(fmaf(eV0,g3.y,1.f));
        const float s7 = (aV0-g3.z)*__builtin_amdgcn_rcpf(fmaf(eV0,g3.w,1.f));
        const bf16x8 afr = mkfrag(cvtpk(s0,s1), cvtpk(s2,s3), cvtpk(s4,s5), cvtpk(s6,s7));
        accB0 = __builtin_amdgcn_mfma_f32_16x16x32_bf16(afr, wfr, accB0, 0, 0, 0);
      }
      {
        const float4* src = PVF4 + (((et0+1)*16 + ks)*4 + lg)*64 + lm;
        const float4 g0 = src[0], g1 = src[16], g2 = src[32], g3 = src[48];
        const float s0 = (aV1-g0.x)*__builtin_amdgcn_rcpf(fmaf(eV1,g0.y,1.f));
        const float s1 = (aV1-g0.z)*__builtin_amdgcn_rcpf(fmaf(eV1,g0.w,1.f));
        const float s2 = (aV1-g1.x)*__builtin_amdgcn_rcpf(fmaf(eV1,g1.y,1.f));
        const float s3 = (aV1-g1.z)*__builtin_amdgcn_rcpf(fmaf(eV1,g1.w,1.f));
        const float s4 = (aV1-g2.x)*__builtin_amdgcn_rcpf(fmaf(eV1,g2.y,1.f));
        const float s5 = (aV1-g2.z)*__builtin_amdgcn_rcpf(fmaf(eV1,g2.w,1.f));
        const float s6 = (aV1-g3.x)*__builtin_amdgcn_rcpf(fmaf(eV1,g3.y,1.f));
        const float s7 = (aV1-g3.z)*__builtin_amdgcn_rcpf(fmaf(eV1,g3.w,1.f));
        const bf16x8 afr = mkfrag(cvtpk(s0,s1), cvtpk(s2,s3), cvtpk(s4,s5), cvtpk(s6,s7));
        accB1 = __builtin_amdgcn_mfma_f32_16x16x32_bf16(afr, wfr, accB1, 0, 0, 0);
      }
    }
    if (lm < HH) {
#pragma unroll
      for (int g = 0; g < 4; ++g) {
        GhL[lm*258 + et0*16 + lg*4 + g]     = accB0[g];
        GhL[lm*258 + (et0+1)*16 + lg*4 + g] = accB1[g];
      }
    }
  }

  // ---- Phase C: context1[c] = sum_j w[h(c),j] * v[j,c] ----
  {
    const int c = t & 255, half = t >> 8, h = c >> 5;
    float a0 = 0.f;
    for (int j = half*256; j < half*256 + 256; ++j)
      a0 += us2f(wtl[j*17 + h]) * vpf[j*DD + c];
    c1h[half*DD + c] = a0;
  }
  __syncthreads();

  // ---- Phase D: context2 = G @ rv2^T + rv2_b; residual + LN2 ----
  float x2v = 0.f;
  if (t < DD) {
    const int c = t, h = c >> 5;
    float a0 = 0.f;
    for (int e = 0; e < DD; ++e) a0 += GhL[h*258 + e] * rv2t[e*DD + c];
    x2v = x[i*DD + c] + c1h[c] + c1h[DD + c] + a0 + rv2_b[c];
  }
  float s = wredSum(x2v);
  if (lane == 0) red[wid] = s;
  __syncthreads();
  const float mu = (red[0]+red[1]+red[2]+red[3]) * (1.0f/DD);
  const float dv = (t < DD) ? (x2v - mu) : 0.f;
  float s2 = wredSum(dv*dv);
  __syncthreads();
  if (lane == 0) red[wid] = s2;
  __syncthreads();
  const float var = (red[0]+red[1]+red[2]+red[3]) * (1.0f/DD);
  const float rstd = rsqrtf(var + 1e-5f);
  if (t < DD) {
    ws[OFF_X2  + i*DD + t] = x2v;
    ws[OFF_XN2 + i*DD + t] = (x2v - mu)*rstd*ln2_w[t] + ln2_b[t];
  }
}

// ---------- K4: SwiGLU up-projections + W3P pack (rep==3) ----------
__global__ __launch_bounds__(256) void k4_ffn1(
    float* __restrict__ ws, const float* __restrict__ b1,
    const float* __restrict__ b2, const float* __restrict__ w3)
{
  const int rep = blockIdx.y, t = threadIdx.x;
  if (rep == 3) {                      // pack w3 k-major into vacated Q region
    float2* dst = (float2*)(ws + OFF_W3P);
    for (int L2 = blockIdx.x*256 + t; L2 < 87296; L2 += 256*256) {
      const int c = L2 & 255, k2i = L2 >> 8;
      dst[L2] = *(const float2*)(w3 + c*HIDN + 2*k2i);
    }
    return;
  }
  const int i0 = blockIdx.x*2;
  const int O = rep*DD + t;
  if (O >= HIDN) return;
  const float4* xn4 = (const float4*)(ws + OFF_XN2);
  const float4* wp4 = (const float4*)(ws + OFF_W12P);
  float a10 = b1[O], a11 = a10;
  float a20 = b2[O], a21 = a20;
  for (int k4 = 0; k4 < 64; ++k4) {
    const float4 u = wp4[(k4*HIDN + O)*2];
    const float4 v = wp4[(k4*HIDN + O)*2 + 1];
    const float4 x0 = xn4[i0*64 + k4];        // uniform -> s_load
    const float4 x1 = xn4[i0*64 + 64 + k4];
    a10 += dot4(x0, u); a20 += dot4(x0, v);
    a11 += dot4(x1, u); a21 += dot4(x1, v);
  }
  ws[OFF_H1 + i0*HIDN + O]     = fsilu(a10)*a20;
  ws[OFF_H1 + (i0+1)*HIDN + O] = fsilu(a11)*a21;
}

// ---------- K5: down-projection + residual ----------
__global__ __launch_bounds__(256) void k5_ffn2(
    const float* __restrict__ ws, const float* __restrict__ b3, float* __restrict__ out)
{
  const int i = blockIdx.x, c = threadIdx.x;
  const float2* wp2 = (const float2*)(ws + OFF_W3P);
  const float2* h2  = (const float2*)(ws + OFF_H1 + i*HIDN);
  float acc = b3[c] + ws[OFF_X2 + i*DD + c];
  for (int k = 0; k < 341; ++k) {
    const float2 w = wp2[k*DD + c];
    const float2 h = h2[k];                   // uniform -> s_load
    acc += h.x*w.x + h.y*w.y;
  }
  out[i*DD + c] = acc;
}

extern "C" void kernel_launch(void* const* d_in, const int* in_sizes, int n_in,
                              void* d_out, int out_size, void* d_ws, size_t ws_size,
                              hipStream_t stream) {
  (void)in_sizes; (void)n_in; (void)out_size; (void)ws_size;
  const float* x      = (const float*)d_in[0];
  const float* coords = (const float*)d_in[1];
  const float* ln1_w  = (const float*)d_in[2];
  const float* ln1_b  = (const float*)d_in[3];
  const float* ln2_w  = (const float*)d_in[4];
  const float* ln2_b  = (const float*)d_in[5];
  const float* qkv_w  = (const float*)d_in[6];
  const float* qkv_b  = (const float*)d_in[7];
  const float* rb1_w  = (const float*)d_in[8];
  const float* rb1_b  = (const float*)d_in[9];
  const float* rb2_w  = (const float*)d_in[10];
  /* d_in[11] = rb2_b cancels in softmax */
  const float* rv1_w  = (const float*)d_in[12];
  const float* rv1_b  = (const float*)d_in[13];
  const float* rv2_w  = (const float*)d_in[14];
  const float* rv2_b  = (const float*)d_in[15];
  const float* ffn_w1 = (const float*)d_in[16];
  const float* ffn_b1 = (const float*)d_in[17];
  const float* ffn_w2 = (const float*)d_in[18];
  const float* ffn_b2 = (const float*)d_in[19];
  const float* ffn_w3 = (const float*)d_in[20];
  const float* ffn_b3 = (const float*)d_in[21];
  float* ws  = (float*)d_ws;
  float* out = (float*)d_out;

  k1_prep<<<1033, 256, 0, stream>>>(x, coords, ln1_w, ln1_b, rb1_w, rv1_w,
                                    rv2_w, rb2_w, qkv_w, ffn_w1, ffn_w2, ws);
  k2_qkv<<<dim3(256, 3), 256, 0, stream>>>(ws, qkv_b);
  k3_attn<<<NN, 512, 0, stream>>>(x, coords, rb1_w, rb1_b, rv1_w, rv1_b, rv2_b,
                                  ln2_w, ln2_b, ws);
  k4_ffn1<<<dim3(256, 4), 256, 0, stream>>>(ws, ffn_b1, ffn_b2, ffn_w3);
  k5_ffn2<<<NN, 256, 0, stream>>>(ws, ffn_b3, out);
}